// Round 10
// baseline (22.169 us; speedup 1.0000x reference)
//
#include <hip/hip_runtime.h>

#define BATCH 8
#define NTOK 4096
#define CH 256
#define IMG 1024
#define PATCH 16
#define CHUNKS 32                    // blocks per (batch, input)
#define TPB (NTOK / CHUNKS)          // 128 tokens per block
#define PART_STRIDE 520              // per-block partial: 256 W + 256 S + scalars
#define NBLK_STATS (2 * BATCH * CHUNKS)  // 512
#define SB (NBLK_STATS * PART_STRIDE)    // ws3 base (floats): 64 slots x 8 floats

// ws layout: slab bid (= is_q*256 + b*32 + chunk), PART_STRIDE floats each:
//   [0,256) W  [256,512) S  [512] sum m  [513] sum m*|e|^2  [514] sum |e|^2
// ws3 (at SB): slot (b*8+g): tx,ty,tz,tw, cnt,np,A,Bv
//
// R8 measured stats ~= 12.4 us (~BW ceiling). R9 showed finalize ~8 us:
// one CU per batch reading 128 KB of cross-XCD partials is MSHR-bound
// (~15 GB/s/CU). R10 spreads the reduce over 64 CUs (mid) + tiny tail.

__device__ __forceinline__ float wave_reduce_sum(float v) {
    for (int off = 32; off > 0; off >>= 1) v += __shfl_down(v, off, 64);
    return v;
}

__global__ __launch_bounds__(256) void stats_kernel(
    const float* __restrict__ ep_e, const float* __restrict__ ep_m,
    const float* __restrict__ q_e,  const float* __restrict__ q_m,
    float* __restrict__ ws)
{
    const int bid = blockIdx.x;
    const int tid = threadIdx.x;

    const bool is_q = (bid >= BATCH * CHUNKS);
    const int lb    = bid & (BATCH * CHUNKS - 1);
    const int b     = lb >> 5;                  // /CHUNKS
    const int start = (lb & (CHUNKS - 1)) * TPB;

    const float* __restrict__ embed = is_q ? q_e : ep_e;
    const float* __restrict__ mask  = is_q ? q_m : ep_m;

    const int w = tid >> 6, lane = tid & 63, cbase = lane << 2;

    float4 accW = {0.f, 0.f, 0.f, 0.f};
    float4 accS = {0.f, 0.f, 0.f, 0.f};
    float accA = 0.f, accB = 0.f, accm = 0.f;

    const float* ebase = embed + (size_t)(b * NTOK + start) * CH + cbase;
    const size_t mbase = (size_t)b * IMG * IMG;

    const int t0 = w * 32;   // this wave's 32 contiguous tokens
    #pragma unroll
    for (int bat = 0; bat < 4; ++bat) {
        float4 e[8];
        float  mm[8];
        #pragma unroll
        for (int k = 0; k < 8; ++k) {
            const int t = t0 + bat * 8 + k;
            const int n = start + t;
            mm[k] = mask[mbase + (size_t)((n >> 6) * PATCH) * IMG + (size_t)((n & 63) * PATCH)];
            e[k]  = *reinterpret_cast<const float4*>(ebase + (size_t)t * CH);
        }
        #pragma unroll
        for (int k = 0; k < 8; ++k) {
            const float m = mm[k];
            accW.x += m * e[k].x; accW.y += m * e[k].y;
            accW.z += m * e[k].z; accW.w += m * e[k].w;
            accS.x += e[k].x;     accS.y += e[k].y;
            accS.z += e[k].z;     accS.w += e[k].w;
            if (is_q) {
                const float d = e[k].x * e[k].x + e[k].y * e[k].y
                              + e[k].z * e[k].z + e[k].w * e[k].w;
                accA += m * d;
                accB += d;
            }
            accm += m;   // wave-uniform
        }
    }

    // cross-wave reduce (all 4 waves cover the same 256 channels)
    __shared__ __align__(16) float ldsW[4][CH];
    __shared__ __align__(16) float ldsS[4][CH];
    __shared__ float ldsA[4], ldsB[4], ldsM[4];

    *reinterpret_cast<float4*>(&ldsW[w][cbase]) = accW;
    *reinterpret_cast<float4*>(&ldsS[w][cbase]) = accS;
    if (is_q) {
        accA = wave_reduce_sum(accA);
        accB = wave_reduce_sum(accB);
    }
    if (lane == 0) { ldsA[w] = accA; ldsB[w] = accB; ldsM[w] = accm; }
    __syncthreads();

    float* p = ws + (size_t)bid * PART_STRIDE;
    const int c = tid;
    p[c]      = ldsW[0][c] + ldsW[1][c] + ldsW[2][c] + ldsW[3][c];
    p[CH + c] = ldsS[0][c] + ldsS[1][c] + ldsS[2][c] + ldsS[3][c];
    if (tid == 0) {
        p[512] = ldsM[0] + ldsM[1] + ldsM[2] + ldsM[3];
        p[513] = is_q ? (ldsA[0] + ldsA[1] + ldsA[2] + ldsA[3]) : 0.f;
        p[514] = is_q ? (ldsB[0] + ldsB[1] + ldsB[2] + ldsB[3]) : 0.f;
    }
}

// 64 blocks: block (b,g) reduces channel slice [g*32, g*32+32) over all 32
// chunks (~20 KB of partials) and emits per-slice partial dot products.
__global__ __launch_bounds__(256) void mid_kernel(float* __restrict__ ws)
{
    const int b   = blockIdx.x >> 3;    // batch
    const int g   = blockIdx.x & 7;     // channel slice
    const int tid = threadIdx.x;
    const int r   = tid >> 5;           // 0..7 chunk row
    const int c   = tid & 31;           // channel within slice
    const int ch  = g * 32 + c;

    // main partial sums: chunks k = r + 8p  (4 per thread, coalesced 128B rows)
    float pn = 0.f, se = 0.f, uu = 0.f, vv = 0.f;
    #pragma unroll
    for (int p = 0; p < 4; ++p) {
        const int k = r + 8 * p;
        const float* pe = ws + (size_t)(b * CHUNKS + k) * PART_STRIDE;
        const float* pq = pe + (size_t)(BATCH * CHUNKS) * PART_STRIDE;
        pn += pe[ch]; se += pe[CH + ch];
        uu += pq[ch]; vv += pq[CH + ch];
    }

    // batch scalars (redundant per block, cheap: 64 cache lines)
    __shared__ float s_sc[4];   // cnt, np, A, Bv
    if (tid < 32) {
        const float* pe = ws + (size_t)(b * CHUNKS + tid) * PART_STRIDE;
        float v = pe[512];
        #pragma unroll
        for (int off = 16; off; off >>= 1) v += __shfl_xor(v, off, 32);
        if (tid == 0) s_sc[0] = v;
    } else if (tid < 64) {
        const float* pq = ws + (size_t)(BATCH * CHUNKS + b * CHUNKS + (tid - 32)) * PART_STRIDE;
        float n0 = pq[512], a0 = pq[513], b0 = pq[514];
        #pragma unroll
        for (int off = 16; off; off >>= 1) {
            n0 += __shfl_xor(n0, off, 32);
            a0 += __shfl_xor(a0, off, 32);
            b0 += __shfl_xor(b0, off, 32);
        }
        if (tid == 32) { s_sc[1] = n0; s_sc[2] = a0; s_sc[3] = b0; }
    }

    __shared__ float ldsm[4][8][32];
    ldsm[0][r][c] = pn; ldsm[1][r][c] = se;
    ldsm[2][r][c] = uu; ldsm[3][r][c] = vv;
    __syncthreads();

    if (tid < 32) {
        float PN = 0.f, SE = 0.f, UU = 0.f, VV = 0.f;
        #pragma unroll
        for (int rr = 0; rr < 8; ++rr) {
            PN += ldsm[0][rr][tid]; SE += ldsm[1][rr][tid];
            UU += ldsm[2][rr][tid]; VV += ldsm[3][rr][tid];
        }
        const float cnt  = s_sc[0];
        const float id_p = 1.f / (cnt + 0.1f);
        const float id_n = 1.f / (((float)NTOK - cnt) + 0.1f);
        const float pc = PN * id_p;
        const float nc = (SE - PN) * id_n;
        float tx = UU * pc;            // partial u.p over this slice
        float ty = (VV - UU) * nc;     // partial (v-u).n
        float tz = pc * pc;            // partial |p|^2
        float tw = nc * nc;            // partial |n|^2
        #pragma unroll
        for (int off = 16; off; off >>= 1) {
            tx += __shfl_xor(tx, off, 32);
            ty += __shfl_xor(ty, off, 32);
            tz += __shfl_xor(tz, off, 32);
            tw += __shfl_xor(tw, off, 32);
        }
        if (tid == 0) {
            float* o = ws + SB + (size_t)(b * 8 + g) * 8;
            o[0] = tx; o[1] = ty; o[2] = tz; o[3] = tw;
            o[4] = s_sc[0]; o[5] = s_sc[1]; o[6] = s_sc[2]; o[7] = s_sc[3];
        }
    }
}

// 1 block x 64 lanes: lane l = b*8+g. Width-8 reduce over g, loss math on
// g==0 lanes, full-wave reduce over batches, plain stores to out.
__global__ __launch_bounds__(64) void tail_kernel(
    const float* __restrict__ ws, float* __restrict__ out)
{
    const int l = threadIdx.x;
    const float* o  = ws + SB + (size_t)l * 8;
    const float* o0 = ws + SB + (size_t)(l & ~7) * 8;
    float tx = o[0], ty = o[1], tz = o[2], tw = o[3];
    const float cnt = o0[4], np = o0[5], A = o0[6], Bv = o0[7];
    (void)cnt;
    #pragma unroll
    for (int off = 4; off; off >>= 1) {
        tx += __shfl_xor(tx, off, 8);
        ty += __shfl_xor(ty, off, 8);
        tz += __shfl_xor(tz, off, 8);
        tw += __shfl_xor(tw, off, 8);
    }
    float pl = 0.f, nl = 0.f;
    if ((l & 7) == 0) {
        const float nn = (float)NTOK - np;
        const float pos_term = A - 2.f * tx + np * tz;
        const float neg_term = (Bv - A) - 2.f * ty + nn * tw;
        pl = (np > 0.f) ? pos_term / (fmaxf(np, 1.f) * (float)CH) : 0.f;
        nl = (nn > 0.f) ? neg_term / (fmaxf(nn, 1.f) * (float)CH) : 0.f;
    }
    #pragma unroll
    for (int off = 32; off; off >>= 1) {
        pl += __shfl_xor(pl, off, 64);
        nl += __shfl_xor(nl, off, 64);
    }
    if (l == 0) {
        const float inv_b = 1.f / (float)BATCH;
        out[0] = (pl + nl) * inv_b;    // mean(center_loss)
        out[1] = pl * inv_b;           // mean(pos_loss)
        out[2] = nl * inv_b;           // mean(neg_loss)
    }
}

extern "C" void kernel_launch(void* const* d_in, const int* in_sizes, int n_in,
                              void* d_out, int out_size, void* d_ws, size_t ws_size,
                              hipStream_t stream) {
    const float* ep_e = (const float*)d_in[0];  // ep_mask_embed (8,4096,256)
    const float* ep_m = (const float*)d_in[1];  // ep_mask (8,1,1024,1024)
    const float* q_e  = (const float*)d_in[2];  // query_mask_embed
    const float* q_m  = (const float*)d_in[3];  // query_mask
    float* out = (float*)d_out;
    float* ws  = (float*)d_ws;

    stats_kernel<<<NBLK_STATS, 256, 0, stream>>>(ep_e, ep_m, q_e, q_m, ws);
    mid_kernel<<<BATCH * 8, 256, 0, stream>>>(ws);
    tail_kernel<<<1, 64, 0, stream>>>(ws, out);
}